// Round 9
// baseline (603.158 us; speedup 1.0000x reference)
//
#include <hip/hip_runtime.h>
#include <hip/hip_cooperative_groups.h>

namespace cg = cooperative_groups;

// Problem constants (from reference setup_inputs)
constexpr int N = 50000;   // nodes
constexpr int E = 800000;  // edges
constexpr int F = 128;     // feature dim
constexpr int U = 256;     // output units

constexpr int R    = 8;        // counter replicas per row (contention /8)
constexpr int NK   = N * R;    // 400000 keys
constexpr int EBLK = E / 256;  // 3125 (exact)
constexpr int SBLK = (NK + 255) / 256;  // 1563

typedef __attribute__((ext_vector_type(8))) short short8;
typedef __attribute__((ext_vector_type(4))) float float4v;

// packed[key]: high 24 bits = edge count, low 40 bits = sum(val) * 2^26
constexpr float FIXED_SCALE = 67108864.0f;             // 2^26
constexpr float FIXED_INV   = 1.4901161193847656e-8f;  // 2^-26
constexpr unsigned long long VAL_MASK = 0xFFFFFFFFFFull;

__device__ inline unsigned short f32_to_bf16(float x) {
    unsigned int u = __float_as_uint(x);
    unsigned int r = (u + 0x7fffu + ((u >> 16) & 1u)) >> 16;  // RNE
    return (unsigned short)r;
}
__device__ inline float bf_lo(unsigned int u) { return __uint_as_float(u << 16); }
__device__ inline float bf_hi(unsigned int u) { return __uint_as_float(u & 0xffff0000u); }

// ===========================================================================
// Phase bodies (shared by the cooperative mega-kernel and discrete fallback)
// ===========================================================================
__device__ inline void p_zero(unsigned long long* packed, int g0, int gsz) {
    for (int i = g0; i < NK; i += gsz) packed[i] = 0ull;
}

__device__ inline void p_hist(const int* erow, const float* eval,
                              unsigned long long* packed, unsigned int* rankp,
                              const float* W, unsigned short* Wt, int g0, int gsz) {
    for (int e = g0; e < E; e += gsz) {
        int key = erow[e] * R + ((e >> 8) & (R - 1));   // key < 400000 < 2^19
        unsigned long long add =
            (1ull << 40) | (unsigned long long)(eval[e] * FIXED_SCALE);
        unsigned long long old = atomicAdd(&packed[key], add);
        rankp[e] = ((unsigned int)key << 12) | (unsigned int)(old >> 40);  // rank < 4096
    }
    for (int idx = g0; idx < F * U; idx += gsz) {  // W [128,256] -> Wt [256,128] bf16
        int k = idx >> 8, n = idx & 255;
        Wt[n * F + k] = f32_to_bf16(W[idx]);
    }
}

__device__ inline void p_blksum(const unsigned long long* packed, int* blk_sum,
                                int bid0, int bstride, int t) {
    __shared__ int s4[4];
    for (int c = bid0; c < SBLK; c += bstride) {
        int i = c * 256 + t;
        int v = (i < NK) ? (int)(packed[i] >> 40) : 0;
        #pragma unroll
        for (int off = 32; off > 0; off >>= 1) v += __shfl_down(v, off, 64);
        if ((t & 63) == 0) s4[t >> 6] = v;
        __syncthreads();
        if (t == 0) blk_sum[c] = s4[0] + s4[1] + s4[2] + s4[3];
        __syncthreads();
    }
}

__device__ inline void p_blkscan(const unsigned long long* packed, const int* blk_sum,
                                 int* rp2, int bid0, int bstride, int t, int g0) {
    __shared__ int sh[256];
    __shared__ int waves[4];
    __shared__ int base_sh;
    for (int c = bid0; c < SBLK; c += bstride) {
        // global offset = sum of blk_sum[idx] for idx < c   (<=7 loads/thread)
        int pre = 0;
        for (int idx = t; idx < c; idx += 256) pre += blk_sum[idx];
        #pragma unroll
        for (int off = 32; off > 0; off >>= 1) pre += __shfl_down(pre, off, 64);
        if ((t & 63) == 0) waves[t >> 6] = pre;
        __syncthreads();
        if (t == 0) base_sh = waves[0] + waves[1] + waves[2] + waves[3];
        int i = c * 256 + t;
        int v = (i < NK) ? (int)(packed[i] >> 40) : 0;
        sh[t] = v;
        __syncthreads();
        for (int off = 1; off < 256; off <<= 1) {
            int u = (t >= off) ? sh[t - off] : 0;
            __syncthreads();
            sh[t] += u;
            __syncthreads();
        }
        if (i < NK) rp2[i] = base_sh + sh[t] - v;
        __syncthreads();
    }
    if (g0 == 0) rp2[NK] = E;
}

__device__ inline void p_permute_norm(const int* ecol, const float* eval,
                                      const unsigned int* rankp, const int* rp2,
                                      int2* csr, const unsigned long long* packed,
                                      const float* feat, float* iv, unsigned int* nrm,
                                      int g0, int gsz, int t) {
    for (int e = g0; e < E; e += gsz) {  // permute: no atomics, no erow re-read
        unsigned int pk = rankp[e];
        int p = rp2[pk >> 12] + (int)(pk & 0xFFFu);
        csr[p] = make_int2(ecol[e], __float_as_int(eval[e]));
    }
    int lane = t & 63;                   // norm: wave per node (independent of csr)
    int w0 = g0 >> 6;
    int wstride = gsz >> 6;
    for (int n = w0; n < N; n += wstride) {
        int kb = n * R;
        unsigned long long s = 0;
        #pragma unroll
        for (int j = 0; j < R; ++j) s += packed[kb + j] & VAL_MASK;
        float iv_ = rsqrtf((float)s * FIXED_INV + 1.0f);
        if (lane == 0) iv[n] = iv_;
        float2 f = ((const float2*)feat)[n * 64 + lane];
        nrm[n * 64 + lane] =
            (unsigned int)f32_to_bf16(iv_ * f.x) | ((unsigned int)f32_to_bf16(iv_ * f.y) << 16);
    }
}

// ===========================================================================
// Cooperative mega-kernel: zero -> hist+wt -> blksum -> blkscan -> permute+norm
// ===========================================================================
__global__ __launch_bounds__(256) void fused_front_kernel(
    const int* __restrict__ erow, const float* __restrict__ eval,
    const int* __restrict__ ecol, const float* __restrict__ W,
    const float* __restrict__ feat,
    unsigned long long* __restrict__ packed, unsigned int* __restrict__ rankp,
    int* __restrict__ blk_sum, int* __restrict__ rp2,
    int2* __restrict__ csr, float* __restrict__ iv,
    unsigned short* __restrict__ Wt, unsigned int* __restrict__ nrm) {
    cg::grid_group grid = cg::this_grid();
    const int nb  = gridDim.x;
    const int gsz = nb * 256;
    const int t   = threadIdx.x;
    const int g0  = blockIdx.x * 256 + t;

    p_zero(packed, g0, gsz);
    grid.sync();
    p_hist(erow, eval, packed, rankp, W, Wt, g0, gsz);
    grid.sync();
    p_blksum(packed, blk_sum, blockIdx.x, nb, t);
    grid.sync();
    p_blkscan(packed, blk_sum, rp2, blockIdx.x, nb, t, g0);
    grid.sync();
    p_permute_norm(ecol, eval, rankp, rp2, csr, packed, feat, iv, nrm, g0, gsz, t);
}

// ===========================================================================
// Discrete fallback kernels (same phase bodies)
// ===========================================================================
__global__ __launch_bounds__(256) void hist_kernel(const int* __restrict__ erow,
                                                   const float* __restrict__ eval,
                                                   unsigned long long* __restrict__ packed,
                                                   unsigned int* __restrict__ rankp,
                                                   const float* __restrict__ W,
                                                   unsigned short* __restrict__ Wt) {
    p_hist(erow, eval, packed, rankp, W, Wt,
           blockIdx.x * 256 + threadIdx.x, gridDim.x * 256);
}
__global__ __launch_bounds__(256) void blksum_kernel(const unsigned long long* __restrict__ packed,
                                                     int* __restrict__ blk_sum) {
    p_blksum(packed, blk_sum, blockIdx.x, gridDim.x, threadIdx.x);
}
__global__ __launch_bounds__(256) void blkscan_kernel(const unsigned long long* __restrict__ packed,
                                                      const int* __restrict__ blk_sum,
                                                      int* __restrict__ rp2) {
    p_blkscan(packed, blk_sum, rp2, blockIdx.x, gridDim.x, threadIdx.x,
              blockIdx.x * 256 + threadIdx.x);
}
__global__ __launch_bounds__(256) void pn_kernel(const int* __restrict__ ecol,
                                                 const float* __restrict__ eval,
                                                 const unsigned int* __restrict__ rankp,
                                                 const int* __restrict__ rp2,
                                                 int2* __restrict__ csr,
                                                 const unsigned long long* __restrict__ packed,
                                                 const float* __restrict__ feat,
                                                 float* __restrict__ iv,
                                                 unsigned int* __restrict__ nrm) {
    p_permute_norm(ecol, eval, rankp, rp2, csr, packed, feat, iv, nrm,
                   blockIdx.x * 256 + threadIdx.x, gridDim.x * 256, threadIdx.x);
}

// ---------------------------------------------------------------------------
// gather: pooled[n] = iv*nrm[n] + sum_e val*nrm[col]  -> bf16 output
// ---------------------------------------------------------------------------
__global__ __launch_bounds__(256) void gather_kernel(const int* __restrict__ rp2,
                                                     const int2* __restrict__ csr,
                                                     const unsigned int* __restrict__ nrm,
                                                     const float* __restrict__ iv,
                                                     unsigned int* __restrict__ pooledb) {
    int gtid = blockIdx.x * 256 + threadIdx.x;
    int n    = gtid >> 6;
    int lane = threadIdx.x & 63;
    if (n >= N) return;

    float iv_ = iv[n];
    unsigned int self = nrm[n * 64 + lane];
    float acc0 = iv_ * bf_lo(self);
    float acc1 = iv_ * bf_hi(self);

    int e = rp2[n * R], e1 = rp2[n * R + R];
    for (; e + 7 < e1; e += 8) {
        int2 p0 = csr[e],     p1 = csr[e + 1], p2 = csr[e + 2], p3 = csr[e + 3];
        int2 p4 = csr[e + 4], p5 = csr[e + 5], p6 = csr[e + 6], p7 = csr[e + 7];
        unsigned int u0 = nrm[(size_t)p0.x * 64 + lane];
        unsigned int u1 = nrm[(size_t)p1.x * 64 + lane];
        unsigned int u2 = nrm[(size_t)p2.x * 64 + lane];
        unsigned int u3 = nrm[(size_t)p3.x * 64 + lane];
        unsigned int u4 = nrm[(size_t)p4.x * 64 + lane];
        unsigned int u5 = nrm[(size_t)p5.x * 64 + lane];
        unsigned int u6 = nrm[(size_t)p6.x * 64 + lane];
        unsigned int u7 = nrm[(size_t)p7.x * 64 + lane];
        acc0 += __int_as_float(p0.y) * bf_lo(u0); acc1 += __int_as_float(p0.y) * bf_hi(u0);
        acc0 += __int_as_float(p1.y) * bf_lo(u1); acc1 += __int_as_float(p1.y) * bf_hi(u1);
        acc0 += __int_as_float(p2.y) * bf_lo(u2); acc1 += __int_as_float(p2.y) * bf_hi(u2);
        acc0 += __int_as_float(p3.y) * bf_lo(u3); acc1 += __int_as_float(p3.y) * bf_hi(u3);
        acc0 += __int_as_float(p4.y) * bf_lo(u4); acc1 += __int_as_float(p4.y) * bf_hi(u4);
        acc0 += __int_as_float(p5.y) * bf_lo(u5); acc1 += __int_as_float(p5.y) * bf_hi(u5);
        acc0 += __int_as_float(p6.y) * bf_lo(u6); acc1 += __int_as_float(p6.y) * bf_hi(u6);
        acc0 += __int_as_float(p7.y) * bf_lo(u7); acc1 += __int_as_float(p7.y) * bf_hi(u7);
    }
    for (; e + 3 < e1; e += 4) {
        int2 p0 = csr[e], p1 = csr[e + 1], p2 = csr[e + 2], p3 = csr[e + 3];
        unsigned int u0 = nrm[(size_t)p0.x * 64 + lane];
        unsigned int u1 = nrm[(size_t)p1.x * 64 + lane];
        unsigned int u2 = nrm[(size_t)p2.x * 64 + lane];
        unsigned int u3 = nrm[(size_t)p3.x * 64 + lane];
        acc0 += __int_as_float(p0.y) * bf_lo(u0); acc1 += __int_as_float(p0.y) * bf_hi(u0);
        acc0 += __int_as_float(p1.y) * bf_lo(u1); acc1 += __int_as_float(p1.y) * bf_hi(u1);
        acc0 += __int_as_float(p2.y) * bf_lo(u2); acc1 += __int_as_float(p2.y) * bf_hi(u2);
        acc0 += __int_as_float(p3.y) * bf_lo(u3); acc1 += __int_as_float(p3.y) * bf_hi(u3);
    }
    for (; e < e1; ++e) {
        int2 p0 = csr[e];
        unsigned int u0 = nrm[(size_t)p0.x * 64 + lane];
        acc0 += __int_as_float(p0.y) * bf_lo(u0);
        acc1 += __int_as_float(p0.y) * bf_hi(u0);
    }
    pooledb[n * 64 + lane] =
        (unsigned int)f32_to_bf16(acc0) | ((unsigned int)f32_to_bf16(acc1) << 16);
}

// ---------------------------------------------------------------------------
// gemm: out = relu(pooled_bf16 @ W) via MFMA 16x16x32 bf16 (unchanged)
// ---------------------------------------------------------------------------
__global__ __launch_bounds__(256) void gemm_mfma_kernel(const unsigned short* __restrict__ Ab,
                                                        const unsigned short* __restrict__ Wt,
                                                        float* __restrict__ out) {
    __shared__ unsigned short As[16384];  // 32 KB, [ks(4)][mt(8)][lane(64)][8]
    __shared__ unsigned short Bs[16384];  // 32 KB, [ks(4)][nt(8)][lane(64)][8]
    const int tid = threadIdx.x;
    const int m0 = blockIdx.x * 128;
    const int n0 = blockIdx.y * 128;

    {
        const int r = tid >> 1;
        const int h = tid & 1;
        const int grow = m0 + r;
        const uint4* asrc = (grow < N) ? (const uint4*)(Ab + (size_t)grow * F) : nullptr;
        const uint4* bsrc = (const uint4*)(Wt + (size_t)(n0 + r) * F);
        #pragma unroll
        for (int j = 0; j < 8; ++j) {
            int o = h * 8 + j;
            int ks = o >> 2, quad = o & 3;
            int slot = ((ks * 8 + (r >> 4)) * 64) + (quad << 4) + (r & 15);
            uint4 av = asrc ? asrc[o] : make_uint4(0u, 0u, 0u, 0u);
            ((uint4*)As)[slot] = av;
            ((uint4*)Bs)[slot] = bsrc[o];
        }
    }
    __syncthreads();

    const int wave = tid >> 6;
    const int lane = tid & 63;
    float4v acc[8][2];
    #pragma unroll
    for (int i = 0; i < 8; ++i) {
        acc[i][0] = (float4v){0.f, 0.f, 0.f, 0.f};
        acc[i][1] = (float4v){0.f, 0.f, 0.f, 0.f};
    }

    #pragma unroll
    for (int ks = 0; ks < 4; ++ks) {
        short8 b0 = *(const short8*)&Bs[(((ks * 8 + wave * 2 + 0) * 64) + lane) * 8];
        short8 b1 = *(const short8*)&Bs[(((ks * 8 + wave * 2 + 1) * 64) + lane) * 8];
        #pragma unroll
        for (int mt = 0; mt < 8; ++mt) {
            short8 a = *(const short8*)&As[(((ks * 8 + mt) * 64) + lane) * 8];
            acc[mt][0] = __builtin_amdgcn_mfma_f32_16x16x32_bf16(a, b0, acc[mt][0], 0, 0, 0);
            acc[mt][1] = __builtin_amdgcn_mfma_f32_16x16x32_bf16(a, b1, acc[mt][1], 0, 0, 0);
        }
    }

    const int quad = lane >> 4;
    const int colt = lane & 15;
    #pragma unroll
    for (int mt = 0; mt < 8; ++mt) {
        #pragma unroll
        for (int nt = 0; nt < 2; ++nt) {
            int col = n0 + (wave * 2 + nt) * 16 + colt;
            #pragma unroll
            for (int i = 0; i < 4; ++i) {
                int row = m0 + mt * 16 + quad * 4 + i;
                if (row < N) out[(size_t)row * U + col] = fmaxf(acc[mt][nt][i], 0.f);
            }
        }
    }
}

// ---------------------------------------------------------------------------
extern "C" void kernel_launch(void* const* d_in, const int* in_sizes, int n_in,
                              void* d_out, int out_size, void* d_ws, size_t ws_size,
                              hipStream_t stream) {
    (void)in_sizes; (void)n_in; (void)out_size; (void)ws_size;

    const float* feat = (const float*)d_in[0];  // [N,128]
    const int*   erow = (const int*)d_in[1];    // [E]
    const int*   ecol = (const int*)d_in[2];    // [E]
    const float* eval = (const float*)d_in[3];  // [E]
    const float* W    = (const float*)d_in[4];  // [128,256]
    float* out = (float*)d_out;                 // [N,256]

    // workspace layout (byte offsets, 64B-aligned)
    char* ws = (char*)d_ws;
    unsigned long long* packed = (unsigned long long*)(ws + 0);   // NK u64 (3.2 MB)
    int*            blk_sum = (int*)(ws + 3200000);               // 1563
    int*            rp2     = (int*)(ws + 3206400);               // NK+1 (1.6 MB)
    unsigned int*   rankp   = (unsigned int*)(ws + 4806464);      // E (3.2 MB)
    int2*           csr     = (int2*)(ws + 8006464);              // E int2 (6.4 MB)
    float*          iv      = (float*)(ws + 14406464);            // N (200 KB)
    unsigned short* Wt      = (unsigned short*)(ws + 14606464);   // 64 KB
    unsigned int*   nrm     = (unsigned int*)(ws + 14672000);     // N*F bf16 (12.8 MB)
    unsigned int*   pooledb = (unsigned int*)(ws + 27472000);     // N*F bf16 (12.8 MB)
    // total ~40.3 MB

    // ---- front half: cooperative mega-kernel (fallback: discrete launches) ----
    void* kargs[] = {(void*)&erow, (void*)&eval, (void*)&ecol, (void*)&W, (void*)&feat,
                     (void*)&packed, (void*)&rankp, (void*)&blk_sum, (void*)&rp2,
                     (void*)&csr, (void*)&iv, (void*)&Wt, (void*)&nrm};
    hipError_t cerr = hipLaunchCooperativeKernel((void*)fused_front_kernel,
                                                 dim3(1024), dim3(256), kargs, 0, stream);
    if (cerr != hipSuccess) {
        (void)hipMemsetAsync(packed, 0, (size_t)NK * 8, stream);
        hist_kernel<<<EBLK, 256, 0, stream>>>(erow, eval, packed, rankp, W, Wt);
        blksum_kernel<<<SBLK, 256, 0, stream>>>(packed, blk_sum);
        blkscan_kernel<<<SBLK, 256, 0, stream>>>(packed, blk_sum, rp2);
        pn_kernel<<<EBLK, 256, 0, stream>>>(ecol, eval, rankp, rp2, csr, packed, feat, iv, nrm);
    }

    gather_kernel<<<(N * 64) / 256, 256, 0, stream>>>(rp2, csr, nrm, iv, pooledb);

    dim3 ggrid((N + 127) / 128, U / 128);
    gemm_mfma_kernel<<<ggrid, 256, 0, stream>>>((const unsigned short*)pooledb, Wt, out);
}

// Round 10
// 215.519 us; speedup vs baseline: 2.7986x; 2.7986x over previous
//
#include <hip/hip_runtime.h>

// Problem constants (from reference setup_inputs)
constexpr int N = 50000;   // nodes
constexpr int E = 800000;  // edges
constexpr int F = 128;     // feature dim
constexpr int U = 256;     // output units

constexpr int R    = 8;        // counter replicas per row (contention /8)
constexpr int NK   = N * R;    // 400000 keys
constexpr int EBLK = E / 256;  // 3125 (exact)
constexpr int SBLK = (NK + 255) / 256;  // 1563

typedef __attribute__((ext_vector_type(8))) short short8;
typedef __attribute__((ext_vector_type(4))) float float4v;

// packed[key]: high 24 bits = edge count, low 40 bits = sum(val) * 2^26
constexpr float FIXED_SCALE = 67108864.0f;             // 2^26
constexpr float FIXED_INV   = 1.4901161193847656e-8f;  // 2^-26
constexpr unsigned long long VAL_MASK = 0xFFFFFFFFFFull;

__device__ inline unsigned short f32_to_bf16(float x) {
    unsigned int u = __float_as_uint(x);
    unsigned int r = (u + 0x7fffu + ((u >> 16) & 1u)) >> 16;  // RNE
    return (unsigned short)r;
}
__device__ inline float bf_lo(unsigned int u) { return __uint_as_float(u << 16); }
__device__ inline float bf_hi(unsigned int u) { return __uint_as_float(u & 0xffff0000u); }

// ---------------------------------------------------------------------------
// 1) hist (+ fused W transpose): ONE u64 atomic per edge on an 8-way
//    replicated packed counter { count<<40 | fixed-point val-sum };
//    returned old value gives rank within the (row, replica) bucket.
// ---------------------------------------------------------------------------
__global__ __launch_bounds__(256) void hist_kernel(const int* __restrict__ erow,
                                                   const float* __restrict__ eval,
                                                   unsigned long long* __restrict__ packed,
                                                   unsigned int* __restrict__ rankp,
                                                   const float* __restrict__ W,
                                                   unsigned short* __restrict__ Wt) {
    if (blockIdx.x >= EBLK) {  // tail blocks: W [128,256] f32 -> Wt [256,128] bf16
        int idx = (blockIdx.x - EBLK) * 256 + threadIdx.x;  // < 32768
        int k = idx >> 8;
        int n = idx & 255;
        Wt[n * F + k] = f32_to_bf16(W[idx]);
        return;
    }
    int e = blockIdx.x * 256 + threadIdx.x;
    int key = erow[e] * R + (blockIdx.x & (R - 1));   // key < 400000 < 2^19
    unsigned long long add =
        (1ull << 40) | (unsigned long long)(eval[e] * FIXED_SCALE);
    unsigned long long old = atomicAdd(&packed[key], add);
    rankp[e] = ((unsigned int)key << 12) | (unsigned int)(old >> 40);  // rank < 4096
}

// ---------------------------------------------------------------------------
// 2a) per-block sums of counts (1563 blocks x 256)
// ---------------------------------------------------------------------------
__global__ __launch_bounds__(256) void blksum_kernel(const unsigned long long* __restrict__ packed,
                                                     int* __restrict__ blk_sum) {
    int i = blockIdx.x * 256 + threadIdx.x;
    int v = (i < NK) ? (int)(packed[i] >> 40) : 0;
    #pragma unroll
    for (int off = 32; off > 0; off >>= 1) v += __shfl_down(v, off, 64);
    __shared__ int s[4];
    if ((threadIdx.x & 63) == 0) s[threadIdx.x >> 6] = v;
    __syncthreads();
    if (threadIdx.x == 0) blk_sum[blockIdx.x] = s[0] + s[1] + s[2] + s[3];
}

// ---------------------------------------------------------------------------
// 2b) merged scan: each block redundantly prefix-sums blk_sum[0..bid)
//     (<=7 loads/thread), then locally scans its 256 counts -> rp2
// ---------------------------------------------------------------------------
__global__ __launch_bounds__(256) void blkscan_kernel(const unsigned long long* __restrict__ packed,
                                                      const int* __restrict__ blk_sum,
                                                      int* __restrict__ rp2) {
    __shared__ int sh[256];
    __shared__ int waves[4];
    __shared__ int base_sh;
    int t = threadIdx.x;
    int bid = blockIdx.x;

    // global offset = sum of blk_sum[idx] for idx < bid
    int pre = 0;
    for (int idx = t; idx < bid; idx += 256) pre += blk_sum[idx];
    #pragma unroll
    for (int off = 32; off > 0; off >>= 1) pre += __shfl_down(pre, off, 64);
    if ((t & 63) == 0) waves[t >> 6] = pre;
    __syncthreads();
    if (t == 0) base_sh = waves[0] + waves[1] + waves[2] + waves[3];

    // local Hillis-Steele over this block's 256 counts
    int i = bid * 256 + t;
    int v = (i < NK) ? (int)(packed[i] >> 40) : 0;
    sh[t] = v;
    __syncthreads();
    for (int off = 1; off < 256; off <<= 1) {
        int u = (t >= off) ? sh[t - off] : 0;
        __syncthreads();
        sh[t] += u;
        __syncthreads();
    }
    if (i < NK) rp2[i] = base_sh + sh[t] - v;
    if (bid == 0 && t == 0) rp2[NK] = E;
}

// ---------------------------------------------------------------------------
// 3) fused permute + norm (independent work, overlapping waves):
//    permute blocks scatter edges into CSR; norm blocks compute iv + bf16 nrm
//    (deg decoded from packed replicas — no csr dependency).
// ---------------------------------------------------------------------------
constexpr int NBLK = (N * 64) / 256;  // 12500 norm blocks
__global__ __launch_bounds__(256) void pn_kernel(const int* __restrict__ ecol,
                                                 const float* __restrict__ eval,
                                                 const unsigned int* __restrict__ rankp,
                                                 const int* __restrict__ rp2,
                                                 int2* __restrict__ csr,
                                                 const unsigned long long* __restrict__ packed,
                                                 const float* __restrict__ feat,
                                                 float* __restrict__ iv,
                                                 unsigned int* __restrict__ nrm) {
    if (blockIdx.x < EBLK) {  // permute: no atomics, no erow re-read
        int e = blockIdx.x * 256 + threadIdx.x;
        unsigned int pk = rankp[e];
        int p = rp2[pk >> 12] + (int)(pk & 0xFFFu);
        csr[p] = make_int2(ecol[e], __float_as_int(eval[e]));
        return;
    }
    int gtid = (blockIdx.x - EBLK) * 256 + threadIdx.x;
    int n    = gtid >> 6;
    int lane = threadIdx.x & 63;
    if (n >= N) return;

    int kb = n * R;
    unsigned long long s = 0;
    #pragma unroll
    for (int j = 0; j < R; ++j) s += packed[kb + j] & VAL_MASK;
    float iv_ = rsqrtf((float)s * FIXED_INV + 1.0f);
    if (lane == 0) iv[n] = iv_;

    float2 f = ((const float2*)feat)[n * 64 + lane];
    nrm[n * 64 + lane] =
        (unsigned int)f32_to_bf16(iv_ * f.x) | ((unsigned int)f32_to_bf16(iv_ * f.y) << 16);
}

// ---------------------------------------------------------------------------
// 4) gather: pooled[n] = iv*nrm[n] + sum_e val*nrm[col]  -> bf16 output
//    wave per node; 8-wide edge unroll for MLP on the csr->nrm chain
// ---------------------------------------------------------------------------
__global__ __launch_bounds__(256) void gather_kernel(const int* __restrict__ rp2,
                                                     const int2* __restrict__ csr,
                                                     const unsigned int* __restrict__ nrm,
                                                     const float* __restrict__ iv,
                                                     unsigned int* __restrict__ pooledb) {
    int gtid = blockIdx.x * 256 + threadIdx.x;
    int n    = gtid >> 6;
    int lane = threadIdx.x & 63;
    if (n >= N) return;

    float iv_ = iv[n];
    unsigned int self = nrm[n * 64 + lane];
    float acc0 = iv_ * bf_lo(self);
    float acc1 = iv_ * bf_hi(self);

    int e = rp2[n * R], e1 = rp2[n * R + R];
    for (; e + 7 < e1; e += 8) {
        int2 p0 = csr[e],     p1 = csr[e + 1], p2 = csr[e + 2], p3 = csr[e + 3];
        int2 p4 = csr[e + 4], p5 = csr[e + 5], p6 = csr[e + 6], p7 = csr[e + 7];
        unsigned int u0 = nrm[(size_t)p0.x * 64 + lane];
        unsigned int u1 = nrm[(size_t)p1.x * 64 + lane];
        unsigned int u2 = nrm[(size_t)p2.x * 64 + lane];
        unsigned int u3 = nrm[(size_t)p3.x * 64 + lane];
        unsigned int u4 = nrm[(size_t)p4.x * 64 + lane];
        unsigned int u5 = nrm[(size_t)p5.x * 64 + lane];
        unsigned int u6 = nrm[(size_t)p6.x * 64 + lane];
        unsigned int u7 = nrm[(size_t)p7.x * 64 + lane];
        acc0 += __int_as_float(p0.y) * bf_lo(u0); acc1 += __int_as_float(p0.y) * bf_hi(u0);
        acc0 += __int_as_float(p1.y) * bf_lo(u1); acc1 += __int_as_float(p1.y) * bf_hi(u1);
        acc0 += __int_as_float(p2.y) * bf_lo(u2); acc1 += __int_as_float(p2.y) * bf_hi(u2);
        acc0 += __int_as_float(p3.y) * bf_lo(u3); acc1 += __int_as_float(p3.y) * bf_hi(u3);
        acc0 += __int_as_float(p4.y) * bf_lo(u4); acc1 += __int_as_float(p4.y) * bf_hi(u4);
        acc0 += __int_as_float(p5.y) * bf_lo(u5); acc1 += __int_as_float(p5.y) * bf_hi(u5);
        acc0 += __int_as_float(p6.y) * bf_lo(u6); acc1 += __int_as_float(p6.y) * bf_hi(u6);
        acc0 += __int_as_float(p7.y) * bf_lo(u7); acc1 += __int_as_float(p7.y) * bf_hi(u7);
    }
    for (; e + 3 < e1; e += 4) {
        int2 p0 = csr[e], p1 = csr[e + 1], p2 = csr[e + 2], p3 = csr[e + 3];
        unsigned int u0 = nrm[(size_t)p0.x * 64 + lane];
        unsigned int u1 = nrm[(size_t)p1.x * 64 + lane];
        unsigned int u2 = nrm[(size_t)p2.x * 64 + lane];
        unsigned int u3 = nrm[(size_t)p3.x * 64 + lane];
        acc0 += __int_as_float(p0.y) * bf_lo(u0); acc1 += __int_as_float(p0.y) * bf_hi(u0);
        acc0 += __int_as_float(p1.y) * bf_lo(u1); acc1 += __int_as_float(p1.y) * bf_hi(u1);
        acc0 += __int_as_float(p2.y) * bf_lo(u2); acc1 += __int_as_float(p2.y) * bf_hi(u2);
        acc0 += __int_as_float(p3.y) * bf_lo(u3); acc1 += __int_as_float(p3.y) * bf_hi(u3);
    }
    for (; e < e1; ++e) {
        int2 p0 = csr[e];
        unsigned int u0 = nrm[(size_t)p0.x * 64 + lane];
        acc0 += __int_as_float(p0.y) * bf_lo(u0);
        acc1 += __int_as_float(p0.y) * bf_hi(u0);
    }
    pooledb[n * 64 + lane] =
        (unsigned int)f32_to_bf16(acc0) | ((unsigned int)f32_to_bf16(acc1) << 16);
}

// ---------------------------------------------------------------------------
// 5) out = relu(pooled_bf16 @ W)  via MFMA 16x16x32 bf16. (unchanged)
// ---------------------------------------------------------------------------
__global__ __launch_bounds__(256) void gemm_mfma_kernel(const unsigned short* __restrict__ Ab,
                                                        const unsigned short* __restrict__ Wt,
                                                        float* __restrict__ out) {
    __shared__ unsigned short As[16384];  // 32 KB, [ks(4)][mt(8)][lane(64)][8]
    __shared__ unsigned short Bs[16384];  // 32 KB, [ks(4)][nt(8)][lane(64)][8]
    const int tid = threadIdx.x;
    const int m0 = blockIdx.x * 128;
    const int n0 = blockIdx.y * 128;

    {
        const int r = tid >> 1;
        const int h = tid & 1;
        const int grow = m0 + r;
        const uint4* asrc = (grow < N) ? (const uint4*)(Ab + (size_t)grow * F) : nullptr;
        const uint4* bsrc = (const uint4*)(Wt + (size_t)(n0 + r) * F);
        #pragma unroll
        for (int j = 0; j < 8; ++j) {
            int o = h * 8 + j;
            int ks = o >> 2, quad = o & 3;
            int slot = ((ks * 8 + (r >> 4)) * 64) + (quad << 4) + (r & 15);
            uint4 av = asrc ? asrc[o] : make_uint4(0u, 0u, 0u, 0u);
            ((uint4*)As)[slot] = av;
            ((uint4*)Bs)[slot] = bsrc[o];
        }
    }
    __syncthreads();

    const int wave = tid >> 6;
    const int lane = tid & 63;
    float4v acc[8][2];
    #pragma unroll
    for (int i = 0; i < 8; ++i) {
        acc[i][0] = (float4v){0.f, 0.f, 0.f, 0.f};
        acc[i][1] = (float4v){0.f, 0.f, 0.f, 0.f};
    }

    #pragma unroll
    for (int ks = 0; ks < 4; ++ks) {
        short8 b0 = *(const short8*)&Bs[(((ks * 8 + wave * 2 + 0) * 64) + lane) * 8];
        short8 b1 = *(const short8*)&Bs[(((ks * 8 + wave * 2 + 1) * 64) + lane) * 8];
        #pragma unroll
        for (int mt = 0; mt < 8; ++mt) {
            short8 a = *(const short8*)&As[(((ks * 8 + mt) * 64) + lane) * 8];
            acc[mt][0] = __builtin_amdgcn_mfma_f32_16x16x32_bf16(a, b0, acc[mt][0], 0, 0, 0);
            acc[mt][1] = __builtin_amdgcn_mfma_f32_16x16x32_bf16(a, b1, acc[mt][1], 0, 0, 0);
        }
    }

    const int quad = lane >> 4;
    const int colt = lane & 15;
    #pragma unroll
    for (int mt = 0; mt < 8; ++mt) {
        #pragma unroll
        for (int nt = 0; nt < 2; ++nt) {
            int col = n0 + (wave * 2 + nt) * 16 + colt;
            #pragma unroll
            for (int i = 0; i < 4; ++i) {
                int row = m0 + mt * 16 + quad * 4 + i;
                if (row < N) out[(size_t)row * U + col] = fmaxf(acc[mt][nt][i], 0.f);
            }
        }
    }
}

// ---------------------------------------------------------------------------
extern "C" void kernel_launch(void* const* d_in, const int* in_sizes, int n_in,
                              void* d_out, int out_size, void* d_ws, size_t ws_size,
                              hipStream_t stream) {
    (void)in_sizes; (void)n_in; (void)out_size; (void)ws_size;

    const float* feat = (const float*)d_in[0];  // [N,128]
    const int*   erow = (const int*)d_in[1];    // [E]
    const int*   ecol = (const int*)d_in[2];    // [E]
    const float* eval = (const float*)d_in[3];  // [E]
    const float* W    = (const float*)d_in[4];  // [128,256]
    float* out = (float*)d_out;                 // [N,256]

    // workspace layout (byte offsets, 64B-aligned)
    char* ws = (char*)d_ws;
    unsigned long long* packed = (unsigned long long*)(ws + 0);   // NK u64 (3.2 MB)
    int*            blk_sum = (int*)(ws + 3200000);               // 1563
    int*            rp2     = (int*)(ws + 3206400);               // NK+1 (1.6 MB)
    unsigned int*   rankp   = (unsigned int*)(ws + 4806464);      // E (3.2 MB)
    int2*           csr     = (int2*)(ws + 8006464);              // E int2 (6.4 MB)
    float*          iv      = (float*)(ws + 14406464);            // N (200 KB)
    unsigned short* Wt      = (unsigned short*)(ws + 14606464);   // 64 KB
    unsigned int*   nrm     = (unsigned int*)(ws + 14672000);     // N*F bf16 (12.8 MB)
    unsigned int*   pooledb = (unsigned int*)(ws + 27472000);     // N*F bf16 (12.8 MB)
    // total ~40.3 MB

    (void)hipMemsetAsync(packed, 0, (size_t)NK * 8, stream);

    hist_kernel<<<EBLK + (F * U) / 256, 256, 0, stream>>>(erow, eval, packed, rankp, W, Wt);

    blksum_kernel <<<SBLK, 256, 0, stream>>>(packed, blk_sum);
    blkscan_kernel<<<SBLK, 256, 0, stream>>>(packed, blk_sum, rp2);

    pn_kernel<<<EBLK + NBLK, 256, 0, stream>>>(ecol, eval, rankp, rp2, csr,
                                               packed, feat, iv, nrm);

    gather_kernel<<<NBLK, 256, 0, stream>>>(rp2, csr, nrm, iv, pooledb);

    dim3 ggrid((N + 127) / 128, U / 128);
    gemm_mfma_kernel<<<ggrid, 256, 0, stream>>>((const unsigned short*)pooledb, Wt, out);
}

// Round 12
// 214.621 us; speedup vs baseline: 2.8103x; 1.0042x over previous
//
#include <hip/hip_runtime.h>

// Problem constants (from reference setup_inputs)
constexpr int N = 50000;   // nodes
constexpr int E = 800000;  // edges
constexpr int F = 128;     // feature dim
constexpr int U = 256;     // output units

constexpr int R    = 8;        // counter replicas per row (contention /8)
constexpr int NK   = N * R;    // 400000 keys
constexpr int EBLK = E / 256;  // 3125 (exact)
constexpr int SBLK = (NK + 255) / 256;  // 1563

typedef __attribute__((ext_vector_type(8))) short short8;
typedef __attribute__((ext_vector_type(4))) float float4v;

// packed[key]: high 24 bits = edge count, low 40 bits = sum(val) * 2^26
constexpr float FIXED_SCALE = 67108864.0f;             // 2^26
constexpr float FIXED_INV   = 1.4901161193847656e-8f;  // 2^-26
constexpr unsigned long long VAL_MASK = 0xFFFFFFFFFFull;

__device__ inline unsigned short f32_to_bf16(float x) {
    unsigned int u = __float_as_uint(x);
    unsigned int r = (u + 0x7fffu + ((u >> 16) & 1u)) >> 16;  // RNE
    return (unsigned short)r;
}
__device__ inline float bf_lo(unsigned int u) { return __uint_as_float(u << 16); }
__device__ inline float bf_hi(unsigned int u) { return __uint_as_float(u & 0xffff0000u); }

// ---------------------------------------------------------------------------
// 1) hist (+ fused W transpose): ONE u64 atomic per edge on an 8-way
//    replicated packed counter { count<<40 | fixed-point val-sum };
//    returned old value gives rank within the (row, replica) bucket.
// ---------------------------------------------------------------------------
__global__ __launch_bounds__(256) void hist_kernel(const int* __restrict__ erow,
                                                   const float* __restrict__ eval,
                                                   unsigned long long* __restrict__ packed,
                                                   unsigned int* __restrict__ rankp,
                                                   const float* __restrict__ W,
                                                   unsigned short* __restrict__ Wt) {
    if (blockIdx.x >= EBLK) {  // tail blocks: W [128,256] f32 -> Wt [256,128] bf16
        int idx = (blockIdx.x - EBLK) * 256 + threadIdx.x;  // < 32768
        int k = idx >> 8;
        int n = idx & 255;
        Wt[n * F + k] = f32_to_bf16(W[idx]);
        return;
    }
    int e = blockIdx.x * 256 + threadIdx.x;
    int key = erow[e] * R + (blockIdx.x & (R - 1));   // key < 400000 < 2^19
    unsigned long long add =
        (1ull << 40) | (unsigned long long)(eval[e] * FIXED_SCALE);
    unsigned long long old = atomicAdd(&packed[key], add);
    rankp[e] = ((unsigned int)key << 12) | (unsigned int)(old >> 40);  // rank < 4096
}

// ---------------------------------------------------------------------------
// 2a) per-block sums of counts (1563 blocks x 256)
// ---------------------------------------------------------------------------
__global__ __launch_bounds__(256) void blksum_kernel(const unsigned long long* __restrict__ packed,
                                                     int* __restrict__ blk_sum) {
    int i = blockIdx.x * 256 + threadIdx.x;
    int v = (i < NK) ? (int)(packed[i] >> 40) : 0;
    #pragma unroll
    for (int off = 32; off > 0; off >>= 1) v += __shfl_down(v, off, 64);
    __shared__ int s[4];
    if ((threadIdx.x & 63) == 0) s[threadIdx.x >> 6] = v;
    __syncthreads();
    if (threadIdx.x == 0) blk_sum[blockIdx.x] = s[0] + s[1] + s[2] + s[3];
}

// ---------------------------------------------------------------------------
// 2b) merged scan: each block redundantly prefix-sums blk_sum[0..bid)
//     (<=7 loads/thread), then locally scans its 256 counts -> rp2
// ---------------------------------------------------------------------------
__global__ __launch_bounds__(256) void blkscan_kernel(const unsigned long long* __restrict__ packed,
                                                      const int* __restrict__ blk_sum,
                                                      int* __restrict__ rp2) {
    __shared__ int sh[256];
    __shared__ int waves[4];
    __shared__ int base_sh;
    int t = threadIdx.x;
    int bid = blockIdx.x;

    // global offset = sum of blk_sum[idx] for idx < bid
    int pre = 0;
    for (int idx = t; idx < bid; idx += 256) pre += blk_sum[idx];
    #pragma unroll
    for (int off = 32; off > 0; off >>= 1) pre += __shfl_down(pre, off, 64);
    if ((t & 63) == 0) waves[t >> 6] = pre;
    __syncthreads();
    if (t == 0) base_sh = waves[0] + waves[1] + waves[2] + waves[3];

    // local Hillis-Steele over this block's 256 counts
    int i = bid * 256 + t;
    int v = (i < NK) ? (int)(packed[i] >> 40) : 0;
    sh[t] = v;
    __syncthreads();
    for (int off = 1; off < 256; off <<= 1) {
        int u = (t >= off) ? sh[t - off] : 0;
        __syncthreads();
        sh[t] += u;
        __syncthreads();
    }
    if (i < NK) rp2[i] = base_sh + sh[t] - v;
    if (bid == 0 && t == 0) rp2[NK] = E;
}

// ---------------------------------------------------------------------------
// 3) fused permute + norm (independent work, overlapping waves):
//    permute blocks scatter edges into CSR; norm blocks compute iv + bf16 nrm
//    (deg decoded from packed replicas — no csr dependency).
// ---------------------------------------------------------------------------
constexpr int NBLK = (N * 64) / 256;  // 12500 norm blocks
__global__ __launch_bounds__(256) void pn_kernel(const int* __restrict__ ecol,
                                                 const float* __restrict__ eval,
                                                 const unsigned int* __restrict__ rankp,
                                                 const int* __restrict__ rp2,
                                                 int2* __restrict__ csr,
                                                 const unsigned long long* __restrict__ packed,
                                                 const float* __restrict__ feat,
                                                 float* __restrict__ iv,
                                                 unsigned int* __restrict__ nrm) {
    if (blockIdx.x < EBLK) {  // permute: no atomics, no erow re-read
        int e = blockIdx.x * 256 + threadIdx.x;
        unsigned int pk = rankp[e];
        int p = rp2[pk >> 12] + (int)(pk & 0xFFFu);
        csr[p] = make_int2(ecol[e], __float_as_int(eval[e]));
        return;
    }
    int gtid = (blockIdx.x - EBLK) * 256 + threadIdx.x;
    int n    = gtid >> 6;
    int lane = threadIdx.x & 63;
    if (n >= N) return;

    int kb = n * R;
    unsigned long long s = 0;
    #pragma unroll
    for (int j = 0; j < R; ++j) s += packed[kb + j] & VAL_MASK;
    float iv_ = rsqrtf((float)s * FIXED_INV + 1.0f);
    if (lane == 0) iv[n] = iv_;

    float2 f = ((const float2*)feat)[n * 64 + lane];
    nrm[n * 64 + lane] =
        (unsigned int)f32_to_bf16(iv_ * f.x) | ((unsigned int)f32_to_bf16(iv_ * f.y) << 16);
}

// ---------------------------------------------------------------------------
// 4) gather: pooled[n] = iv*nrm[n] + sum_e val*nrm[col]  -> bf16 output
//    wave per node; 8-wide edge unroll for MLP on the csr->nrm chain
// ---------------------------------------------------------------------------
__global__ __launch_bounds__(256) void gather_kernel(const int* __restrict__ rp2,
                                                     const int2* __restrict__ csr,
                                                     const unsigned int* __restrict__ nrm,
                                                     const float* __restrict__ iv,
                                                     unsigned int* __restrict__ pooledb) {
    int gtid = blockIdx.x * 256 + threadIdx.x;
    int n    = gtid >> 6;
    int lane = threadIdx.x & 63;
    if (n >= N) return;

    float iv_ = iv[n];
    unsigned int self = nrm[n * 64 + lane];
    float acc0 = iv_ * bf_lo(self);
    float acc1 = iv_ * bf_hi(self);

    int e = rp2[n * R], e1 = rp2[n * R + R];
    for (; e + 7 < e1; e += 8) {
        int2 p0 = csr[e],     p1 = csr[e + 1], p2 = csr[e + 2], p3 = csr[e + 3];
        int2 p4 = csr[e + 4], p5 = csr[e + 5], p6 = csr[e + 6], p7 = csr[e + 7];
        unsigned int u0 = nrm[(size_t)p0.x * 64 + lane];
        unsigned int u1 = nrm[(size_t)p1.x * 64 + lane];
        unsigned int u2 = nrm[(size_t)p2.x * 64 + lane];
        unsigned int u3 = nrm[(size_t)p3.x * 64 + lane];
        unsigned int u4 = nrm[(size_t)p4.x * 64 + lane];
        unsigned int u5 = nrm[(size_t)p5.x * 64 + lane];
        unsigned int u6 = nrm[(size_t)p6.x * 64 + lane];
        unsigned int u7 = nrm[(size_t)p7.x * 64 + lane];
        acc0 += __int_as_float(p0.y) * bf_lo(u0); acc1 += __int_as_float(p0.y) * bf_hi(u0);
        acc0 += __int_as_float(p1.y) * bf_lo(u1); acc1 += __int_as_float(p1.y) * bf_hi(u1);
        acc0 += __int_as_float(p2.y) * bf_lo(u2); acc1 += __int_as_float(p2.y) * bf_hi(u2);
        acc0 += __int_as_float(p3.y) * bf_lo(u3); acc1 += __int_as_float(p3.y) * bf_hi(u3);
        acc0 += __int_as_float(p4.y) * bf_lo(u4); acc1 += __int_as_float(p4.y) * bf_hi(u4);
        acc0 += __int_as_float(p5.y) * bf_lo(u5); acc1 += __int_as_float(p5.y) * bf_hi(u5);
        acc0 += __int_as_float(p6.y) * bf_lo(u6); acc1 += __int_as_float(p6.y) * bf_hi(u6);
        acc0 += __int_as_float(p7.y) * bf_lo(u7); acc1 += __int_as_float(p7.y) * bf_hi(u7);
    }
    for (; e + 3 < e1; e += 4) {
        int2 p0 = csr[e], p1 = csr[e + 1], p2 = csr[e + 2], p3 = csr[e + 3];
        unsigned int u0 = nrm[(size_t)p0.x * 64 + lane];
        unsigned int u1 = nrm[(size_t)p1.x * 64 + lane];
        unsigned int u2 = nrm[(size_t)p2.x * 64 + lane];
        unsigned int u3 = nrm[(size_t)p3.x * 64 + lane];
        acc0 += __int_as_float(p0.y) * bf_lo(u0); acc1 += __int_as_float(p0.y) * bf_hi(u0);
        acc0 += __int_as_float(p1.y) * bf_lo(u1); acc1 += __int_as_float(p1.y) * bf_hi(u1);
        acc0 += __int_as_float(p2.y) * bf_lo(u2); acc1 += __int_as_float(p2.y) * bf_hi(u2);
        acc0 += __int_as_float(p3.y) * bf_lo(u3); acc1 += __int_as_float(p3.y) * bf_hi(u3);
    }
    for (; e < e1; ++e) {
        int2 p0 = csr[e];
        unsigned int u0 = nrm[(size_t)p0.x * 64 + lane];
        acc0 += __int_as_float(p0.y) * bf_lo(u0);
        acc1 += __int_as_float(p0.y) * bf_hi(u0);
    }
    pooledb[n * 64 + lane] =
        (unsigned int)f32_to_bf16(acc0) | ((unsigned int)f32_to_bf16(acc1) << 16);
}

// ---------------------------------------------------------------------------
// 5) out = relu(pooled_bf16 @ W)  via MFMA 16x16x32 bf16. (unchanged)
// ---------------------------------------------------------------------------
__global__ __launch_bounds__(256) void gemm_mfma_kernel(const unsigned short* __restrict__ Ab,
                                                        const unsigned short* __restrict__ Wt,
                                                        float* __restrict__ out) {
    __shared__ unsigned short As[16384];  // 32 KB, [ks(4)][mt(8)][lane(64)][8]
    __shared__ unsigned short Bs[16384];  // 32 KB, [ks(4)][nt(8)][lane(64)][8]
    const int tid = threadIdx.x;
    const int m0 = blockIdx.x * 128;
    const int n0 = blockIdx.y * 128;

    {
        const int r = tid >> 1;
        const int h = tid & 1;
        const int grow = m0 + r;
        const uint4* asrc = (grow < N) ? (const uint4*)(Ab + (size_t)grow * F) : nullptr;
        const uint4* bsrc = (const uint4*)(Wt + (size_t)(n0 + r) * F);
        #pragma unroll
        for (int j = 0; j < 8; ++j) {
            int o = h * 8 + j;
            int ks = o >> 2, quad = o & 3;
            int slot = ((ks * 8 + (r >> 4)) * 64) + (quad << 4) + (r & 15);
            uint4 av = asrc ? asrc[o] : make_uint4(0u, 0u, 0u, 0u);
            ((uint4*)As)[slot] = av;
            ((uint4*)Bs)[slot] = bsrc[o];
        }
    }
    __syncthreads();

    const int wave = tid >> 6;
    const int lane = tid & 63;
    float4v acc[8][2];
    #pragma unroll
    for (int i = 0; i < 8; ++i) {
        acc[i][0] = (float4v){0.f, 0.f, 0.f, 0.f};
        acc[i][1] = (float4v){0.f, 0.f, 0.f, 0.f};
    }

    #pragma unroll
    for (int ks = 0; ks < 4; ++ks) {
        short8 b0 = *(const short8*)&Bs[(((ks * 8 + wave * 2 + 0) * 64) + lane) * 8];
        short8 b1 = *(const short8*)&Bs[(((ks * 8 + wave * 2 + 1) * 64) + lane) * 8];
        #pragma unroll
        for (int mt = 0; mt < 8; ++mt) {
            short8 a = *(const short8*)&As[(((ks * 8 + mt) * 64) + lane) * 8];
            acc[mt][0] = __builtin_amdgcn_mfma_f32_16x16x32_bf16(a, b0, acc[mt][0], 0, 0, 0);
            acc[mt][1] = __builtin_amdgcn_mfma_f32_16x16x32_bf16(a, b1, acc[mt][1], 0, 0, 0);
        }
    }

    const int quad = lane >> 4;
    const int colt = lane & 15;
    #pragma unroll
    for (int mt = 0; mt < 8; ++mt) {
        #pragma unroll
        for (int nt = 0; nt < 2; ++nt) {
            int col = n0 + (wave * 2 + nt) * 16 + colt;
            #pragma unroll
            for (int i = 0; i < 4; ++i) {
                int row = m0 + mt * 16 + quad * 4 + i;
                if (row < N) out[(size_t)row * U + col] = fmaxf(acc[mt][nt][i], 0.f);
            }
        }
    }
}

// ---------------------------------------------------------------------------
extern "C" void kernel_launch(void* const* d_in, const int* in_sizes, int n_in,
                              void* d_out, int out_size, void* d_ws, size_t ws_size,
                              hipStream_t stream) {
    (void)in_sizes; (void)n_in; (void)out_size; (void)ws_size;

    const float* feat = (const float*)d_in[0];  // [N,128]
    const int*   erow = (const int*)d_in[1];    // [E]
    const int*   ecol = (const int*)d_in[2];    // [E]
    const float* eval = (const float*)d_in[3];  // [E]
    const float* W    = (const float*)d_in[4];  // [128,256]
    float* out = (float*)d_out;                 // [N,256]

    // workspace layout (byte offsets, 64B-aligned)
    char* ws = (char*)d_ws;
    unsigned long long* packed = (unsigned long long*)(ws + 0);   // NK u64 (3.2 MB)
    int*            blk_sum = (int*)(ws + 3200000);               // 1563
    int*            rp2     = (int*)(ws + 3206400);               // NK+1 (1.6 MB)
    unsigned int*   rankp   = (unsigned int*)(ws + 4806464);      // E (3.2 MB)
    int2*           csr     = (int2*)(ws + 8006464);              // E int2 (6.4 MB)
    float*          iv      = (float*)(ws + 14406464);            // N (200 KB)
    unsigned short* Wt      = (unsigned short*)(ws + 14606464);   // 64 KB
    unsigned int*   nrm     = (unsigned int*)(ws + 14672000);     // N*F bf16 (12.8 MB)
    unsigned int*   pooledb = (unsigned int*)(ws + 27472000);     // N*F bf16 (12.8 MB)
    // total ~40.3 MB

    (void)hipMemsetAsync(packed, 0, (size_t)NK * 8, stream);

    hist_kernel<<<EBLK + (F * U) / 256, 256, 0, stream>>>(erow, eval, packed, rankp, W, Wt);

    blksum_kernel <<<SBLK, 256, 0, stream>>>(packed, blk_sum);
    blkscan_kernel<<<SBLK, 256, 0, stream>>>(packed, blk_sum, rp2);

    pn_kernel<<<EBLK + NBLK, 256, 0, stream>>>(ecol, eval, rankp, rp2, csr,
                                               packed, feat, iv, nrm);

    gather_kernel<<<NBLK, 256, 0, stream>>>(rp2, csr, nrm, iv, pooledb);

    dim3 ggrid((N + 127) / 128, U / 128);
    gemm_mfma_kernel<<<ggrid, 256, 0, stream>>>((const unsigned short*)pooledb, Wt, out);
}